// Round 7
// baseline (651.354 us; speedup 1.0000x reference)
//
#include <hip/hip_runtime.h>

// Problem constants (B,T,D,H fixed by the reference)
#define BATCH 4
#define SEQ   2048
#define DIM   1024
#define NH    16
#define DK    64
// 0.125 (1/sqrt(DK)) * log2(e): folded into Q so attention uses exp2f
#define QSCALE 0.18033688011112042f

typedef __bf16 bf16x8 __attribute__((ext_vector_type(8)));
typedef float  f32x4  __attribute__((ext_vector_type(4)));
typedef short  s16x4  __attribute__((ext_vector_type(4)));
typedef short  s16x8  __attribute__((ext_vector_type(8)));

__device__ __forceinline__ short f2b(float f) {
    unsigned u = __float_as_uint(f);
    u += 0x7FFFu + ((u >> 16) & 1u);   // RNE
    return (short)(u >> 16);
}

// Load 8 bf16 as shorts, bit-cast in-register (no type-punned memory access).
__device__ __forceinline__ bf16x8 ldb(const short* p) {
    s16x8 v = *(const s16x8*)p;
    return __builtin_bit_cast(bf16x8, v);
}

// async global->LDS, 16B per lane. LDS dest must be linear in lane order.
__device__ __forceinline__ void ld16(const void* g, void* l) {
    __builtin_amdgcn_global_load_lds(
        (__attribute__((address_space(1))) void*)(unsigned long long)g,
        (__attribute__((address_space(3))) void*)l, 16, 0, 0);
}

// ---------------------------------------------------------------------------
// Kernel 1: fp32 -> bf16 conversion of x, W_qkv, W_o
// ---------------------------------------------------------------------------
__global__ __launch_bounds__(256)
void cvt_all(const float* __restrict__ x, const float* __restrict__ wq,
             const float* __restrict__ wo,
             short* __restrict__ xb, short* __restrict__ wqb, short* __restrict__ wob)
{
    const int NX4 = (BATCH*SEQ*DIM) / 4;
    const int NQ4 = (3*DIM*DIM) / 4;
    const int NO4 = (DIM*DIM) / 4;
    const int total = NX4 + NQ4 + NO4;
    for (int u = blockIdx.x * blockDim.x + threadIdx.x; u < total;
         u += gridDim.x * blockDim.x) {
        const float* src; short* dst; int off;
        if (u < NX4)            { src = x;  dst = xb;  off = u; }
        else if (u < NX4 + NQ4) { src = wq; dst = wqb; off = u - NX4; }
        else                    { src = wo; dst = wob; off = u - NX4 - NQ4; }
        f32x4 v = *(const f32x4*)&src[(size_t)off * 4];
        s16x4 o;
        o[0] = f2b(v[0]); o[1] = f2b(v[1]); o[2] = f2b(v[2]); o[3] = f2b(v[3]);
        *(s16x4*)&dst[(size_t)off * 4] = o;
    }
}

// ---------------------------------------------------------------------------
// GEMM (C = A * B^T), m97 pattern: 128x128 tile, BK=64, 4 waves.
// A,B bf16 (shorts), K contiguous.
// QKV=true: scatter to Q (scaled, (B,H,T,DK)), K ((B,H,T,DK)), Vt ((B,H,DK,T)).
// QKV=false: write C as FP32 to Cf (d_out is float per reference dtype).
// ---------------------------------------------------------------------------
template<bool QKV>
__global__ __launch_bounds__(256)
void gemm_bt(const short* __restrict__ A, const short* __restrict__ Bm,
             int M, int N, int K,
             short* __restrict__ C0, short* __restrict__ C1, short* __restrict__ C2,
             float* __restrict__ Cf)
{
    __shared__ short As[128 * 64];
    __shared__ short Bs[128 * 64];
    const int tid  = threadIdx.x;
    const int lane = tid & 63;
    const int lr   = lane & 15;
    const int lg   = lane >> 4;
    const int wid  = tid >> 6;
    const int wr   = wid >> 1, wc = wid & 1;
    const long row0 = (long)blockIdx.y * 128;
    const long col0 = (long)blockIdx.x * 128;

    f32x4 acc[4][4] = {};

    for (int k0 = 0; k0 < K; k0 += 64) {
        #pragma unroll
        for (int i = 0; i < 4; ++i) {               // A tile: 128x64 bf16
            int off = (i * 256 + tid) * 8;
            int r = off >> 6, c = off & 63;
            ld16(&A[(row0 + r) * (long)K + k0 + c], &As[off]);
        }
        #pragma unroll
        for (int i = 0; i < 4; ++i) {               // B tile: 128x64 bf16
            int off = (i * 256 + tid) * 8;
            int r = off >> 6, c = off & 63;
            ld16(&Bm[(col0 + r) * (long)K + k0 + c], &Bs[off]);
        }
        __syncthreads();
        #pragma unroll
        for (int ks = 0; ks < 2; ++ks) {
            bf16x8 af[4], bfr[4];
            #pragma unroll
            for (int m = 0; m < 4; ++m)
                af[m] = ldb(&As[(wr*64 + m*16 + lr)*64 + ks*32 + lg*8]);
            #pragma unroll
            for (int n = 0; n < 4; ++n)
                bfr[n] = ldb(&Bs[(wc*64 + n*16 + lr)*64 + ks*32 + lg*8]);
            #pragma unroll
            for (int m = 0; m < 4; ++m)
                #pragma unroll
                for (int n = 0; n < 4; ++n)
                    acc[m][n] = __builtin_amdgcn_mfma_f32_16x16x32_bf16(
                        af[m], bfr[n], acc[m][n], 0, 0, 0);
        }
        __syncthreads();
    }

    // C/D layout: col = lane&15, row = (lane>>4)*4 + reg
    if (QKV) {
        #pragma unroll
        for (int n = 0; n < 4; ++n) {
            const int gn    = (int)col0 + wc*64 + n*16 + lr;   // 0..3071
            const int which = gn >> 10;                        // 0=Q 1=K 2=V
            const int wi    = gn & 1023;
            const int h = wi >> 6, dk = wi & 63;
            #pragma unroll
            for (int m = 0; m < 4; ++m) {
                const int gm0 = (int)row0 + wr*64 + m*16 + lg*4;
                const int b = gm0 >> 11, t0 = gm0 & 2047;
                if (which == 2) {
                    // V transposed: Vt[(b,h,dk,t)], 4 consecutive t -> 8B store
                    s16x4 v4;
                    #pragma unroll
                    for (int r = 0; r < 4; ++r) v4[r] = f2b(acc[m][n][r]);
                    *(s16x4*)&C2[((long)((b*NH + h)*DK + dk)) * SEQ + t0] = v4;
                } else {
                    short* dst = (which == 0) ? C0 : C1;
                    const float sc = (which == 0) ? QSCALE : 1.0f;
                    #pragma unroll
                    for (int r = 0; r < 4; ++r)
                        dst[((long)((b*NH + h)*SEQ + t0 + r)) * DK + dk] =
                            f2b(acc[m][n][r] * sc);
                }
            }
        }
    } else {
        // FP32 output (d_out dtype = reference output dtype = float32)
        #pragma unroll
        for (int m = 0; m < 4; ++m)
            #pragma unroll
            for (int r = 0; r < 4; ++r) {
                const long gm = row0 + wr*64 + m*16 + lg*4 + r;
                #pragma unroll
                for (int n = 0; n < 4; ++n)
                    Cf[gm * N + col0 + wc*64 + n*16 + lr] = acc[m][n][r];
            }
    }
}

// ---------------------------------------------------------------------------
// Kernel 3: causal flash attention, swapped-operand form.
// grid = (SEQ/64, BATCH*NH), block = 256 (4 waves, 16 q-rows per wave).
// blockIdx.x reversed so longest blocks launch first (tail packing).
//
// S^T = mfma(K,Q): lane owns q = lane&15; holds 16 k-scores per 64-key tile
//   (k = k0 + kt*16 + (lane>>4)*4 + r). Softmax: in-register reduce + 2 shfl.
// O^T = mfma(Vt,P): output col = q = lane&15 -> m/l/corr stay lane-local.
// P transposed via per-wave LDS (4x ds_write_b64 + 2x ds_read_b128 per tile).
// Q pre-scaled by 0.125*log2e; exp2f softmax.
// Q,K: (B,H,T,DK) bf16.  V: (B,H,DK,T) bf16.  O: (B,T,D) bf16.
// ---------------------------------------------------------------------------
__global__ __launch_bounds__(256)
void attn(const short* __restrict__ Qb, const short* __restrict__ Kb,
          const short* __restrict__ Vt, short* __restrict__ Ob)
{
    __shared__ short Pl[4][16 * 72];    // per-wave P buffer: 16 q-rows, stride 72
    const int tid  = threadIdx.x;
    const int lane = tid & 63;
    const int lr   = lane & 15, lg = lane >> 4;
    const int wid  = tid >> 6;
    const int bh   = blockIdx.y;
    const int b    = bh >> 4, h = bh & 15;
    const int qbase = (31 - (int)blockIdx.x) * 64 + wid * 16;

    const short* Qh = Qb + (long)bh * (SEQ * DK);
    const short* Kh = Kb + (long)bh * (SEQ * DK);
    const short* Vh = Vt + (long)bh * (DK * SEQ);
    short* Pw = &Pl[wid][0];

    // Q B-operand fragment: lane holds Q[qbase+lr][ks*32 + lg*8 + j]
    const bf16x8 qf0 = ldb(&Qh[(qbase + lr) * DK + lg * 8]);
    const bf16x8 qf1 = ldb(&Qh[(qbase + lr) * DK + 32 + lg * 8]);

    f32x4 o[4] = {};              // O^T frags: o[n2][r] = O[q=lr][dk=n2*16+lg*4+r]
    float mrow = -1e30f, lrow = 0.f;   // per-lane online softmax state (q = lr)

    const int nfull = qbase >> 6;     // tiles fully below the diagonal
    for (int kt64 = 0; kt64 <= nfull; ++kt64) {
        const int k0 = kt64 << 6;
        // ---- S^T = K * Q^T for 64 keys: s[kt][r] = S[k0+kt*16+lg*4+r][q=lr]
        f32x4 s[4];
        __builtin_amdgcn_s_setprio(1);
        #pragma unroll
        for (int kt = 0; kt < 4; ++kt) {
            const bf16x8 ka = ldb(&Kh[(k0 + kt*16 + lr) * DK + lg * 8]);
            const bf16x8 kb2 = ldb(&Kh[(k0 + kt*16 + lr) * DK + 32 + lg * 8]);
            f32x4 z = {};
            z = __builtin_amdgcn_mfma_f32_16x16x32_bf16(ka, qf0, z, 0, 0, 0);
            s[kt] = __builtin_amdgcn_mfma_f32_16x16x32_bf16(kb2, qf1, z, 0, 0, 0);
        }
        __builtin_amdgcn_s_setprio(0);
        // ---- causal mask (only the diagonal tile)
        if (kt64 == nfull) {
            #pragma unroll
            for (int kt = 0; kt < 4; ++kt)
                #pragma unroll
                for (int r = 0; r < 4; ++r)
                    if (k0 + kt*16 + lg*4 + r > qbase + lr) s[kt][r] = -1e30f;
        }
        // ---- online softmax: lane-local over 16 k, then 2 shfl across groups
        float tm = s[0][0];
        #pragma unroll
        for (int kt = 0; kt < 4; ++kt)
            #pragma unroll
            for (int r = 0; r < 4; ++r) tm = fmaxf(tm, s[kt][r]);
        tm = fmaxf(tm, __shfl_xor(tm, 16));
        tm = fmaxf(tm, __shfl_xor(tm, 32));
        const float mnew = fmaxf(mrow, tm);
        const float corr = exp2f(mrow - mnew);
        mrow = mnew;
        float rs = 0.f;
        #pragma unroll
        for (int kt = 0; kt < 4; ++kt) {
            s16x4 pk;
            #pragma unroll
            for (int r = 0; r < 4; ++r) {
                const float p = exp2f(s[kt][r] - mnew);   // masked -> 0
                rs += p;
                pk[r] = f2b(p);
            }
            *(s16x4*)&Pw[lr*72 + kt*16 + lg*4] = pk;      // P[q=lr][ksub]
        }
        rs += __shfl_xor(rs, 16);
        rs += __shfl_xor(rs, 32);
        lrow = lrow * corr + rs;
        #pragma unroll
        for (int n2 = 0; n2 < 4; ++n2) o[n2] *= corr;
        // ---- P transpose handoff (write -> wait -> read, verified pattern)
        __builtin_amdgcn_sched_barrier(0);
        __builtin_amdgcn_s_waitcnt(0xC07F);   // lgkmcnt(0)
        __builtin_amdgcn_sched_barrier(0);
        const bf16x8 pf0 = ldb(&Pw[lr*72 + lg*8]);        // P[q=lr][k=lg*8+j]
        const bf16x8 pf1 = ldb(&Pw[lr*72 + 32 + lg*8]);
        // ---- O^T += Vt * P^T  (A = Vt rows -> C row = dk, col = q = lr)
        __builtin_amdgcn_s_setprio(1);
        #pragma unroll
        for (int n2 = 0; n2 < 4; ++n2) {
            const bf16x8 v0 = ldb(&Vh[(n2*16 + lr) * SEQ + k0 + lg*8]);
            o[n2] = __builtin_amdgcn_mfma_f32_16x16x32_bf16(v0, pf0, o[n2], 0, 0, 0);
            const bf16x8 v1 = ldb(&Vh[(n2*16 + lr) * SEQ + k0 + 32 + lg*8]);
            o[n2] = __builtin_amdgcn_mfma_f32_16x16x32_bf16(v1, pf1, o[n2], 0, 0, 0);
        }
        __builtin_amdgcn_s_setprio(0);
    }

    const float inv = 1.0f / lrow;
    const long orow = ((long)(b * SEQ + qbase + lr)) * DIM + h * DK;
    #pragma unroll
    for (int n2 = 0; n2 < 4; ++n2) {
        s16x4 ov;
        #pragma unroll
        for (int r = 0; r < 4; ++r) ov[r] = f2b(o[n2][r] * inv);
        *(s16x4*)&Ob[orow + n2*16 + lg*4] = ov;
    }
}

// ---------------------------------------------------------------------------
extern "C" void kernel_launch(void* const* d_in, const int* in_sizes, int n_in,
                              void* d_out, int out_size, void* d_ws, size_t ws_size,
                              hipStream_t stream) {
    // Inputs are FP32 (reference dtypes). Select by size to be order-robust.
    const float *x = nullptr, *wqkv = nullptr, *wo = nullptr;
    for (int i = 0; i < n_in; ++i) {
        if      (in_sizes[i] == BATCH*SEQ*DIM) x    = (const float*)d_in[i];
        else if (in_sizes[i] == 3*DIM*DIM)     wqkv = (const float*)d_in[i];
        else if (in_sizes[i] == DIM*DIM)       wo   = (const float*)d_in[i];
    }
    float* out = (float*)d_out;   // FP32 output (reference output dtype)

    // Workspace (72 MiB; Ob aliases Xb which is dead after the QKV GEMM)
    char* ws = (char*)d_ws;
    short* Xb  = (short*)(ws);                        // [ 0,16) MiB x bf16
    short* Wqb = (short*)(ws + (16u<<20));            // [16,22) W_qkv bf16
    short* Wob = (short*)(ws + (22u<<20));            // [22,24) W_o bf16
    short* Qb  = (short*)(ws + (24u<<20));            // [24,40) Q (B,H,T,DK) scaled
    short* Kb  = (short*)(ws + (40u<<20));            // [40,56) K (B,H,T,DK)
    short* Vt  = (short*)(ws + (56u<<20));            // [56,72) V (B,H,DK,T)
    short* Ob  = Xb;                                  // attn out (B,T,D)

    cvt_all<<<2048, 256, 0, stream>>>(x, wqkv, wo, Xb, Wqb, Wob);

    // QKV projection: M=8192, N=3072, K=1024
    gemm_bt<true><<<dim3(3*DIM/128, BATCH*SEQ/128), 256, 0, stream>>>(
        Xb, Wqb, BATCH*SEQ, 3*DIM, DIM, Qb, Kb, Vt, nullptr);

    attn<<<dim3(SEQ/64, BATCH*NH), 256, 0, stream>>>(Qb, Kb, Vt, Ob);

    // Output projection: M=8192, N=1024, K=1024 -> FP32 d_out
    gemm_bt<false><<<dim3(DIM/128, BATCH*SEQ/128), 256, 0, stream>>>(
        Ob, Wob, BATCH*SEQ, DIM, DIM, nullptr, nullptr, nullptr, out);
}

// Round 8
// 426.779 us; speedup vs baseline: 1.5262x; 1.5262x over previous
//
#include <hip/hip_runtime.h>

// Problem constants (B,T,D,H fixed by the reference)
#define BATCH 4
#define SEQ   2048
#define DIM   1024
#define NH    16
#define DK    64
// 0.125 (1/sqrt(DK)) * log2(e): folded into Q so attention uses exp2f
#define QSCALE 0.18033688011112042f

typedef __bf16 bf16x8 __attribute__((ext_vector_type(8)));
typedef float  f32x4  __attribute__((ext_vector_type(4)));
typedef short  s16x4  __attribute__((ext_vector_type(4)));
typedef short  s16x8  __attribute__((ext_vector_type(8)));

__device__ __forceinline__ short f2b(float f) {
    unsigned u = __float_as_uint(f);
    u += 0x7FFFu + ((u >> 16) & 1u);   // RNE
    return (short)(u >> 16);
}

// Load 8 bf16 as shorts, bit-cast in-register (no type-punned memory access).
__device__ __forceinline__ bf16x8 ldb(const short* p) {
    s16x8 v = *(const s16x8*)p;
    return __builtin_bit_cast(bf16x8, v);
}

// async global->LDS, 16B per lane. LDS dest must be linear in lane order.
__device__ __forceinline__ void ld16(const void* g, void* l) {
    __builtin_amdgcn_global_load_lds(
        (__attribute__((address_space(1))) void*)(unsigned long long)g,
        (__attribute__((address_space(3))) void*)l, 16, 0, 0);
}

// ---------------------------------------------------------------------------
// Kernel 1: fp32 -> bf16 conversion of x, W_qkv, W_o
// ---------------------------------------------------------------------------
__global__ __launch_bounds__(256)
void cvt_all(const float* __restrict__ x, const float* __restrict__ wq,
             const float* __restrict__ wo,
             short* __restrict__ xb, short* __restrict__ wqb, short* __restrict__ wob)
{
    const int NX4 = (BATCH*SEQ*DIM) / 4;
    const int NQ4 = (3*DIM*DIM) / 4;
    const int NO4 = (DIM*DIM) / 4;
    const int total = NX4 + NQ4 + NO4;
    for (int u = blockIdx.x * blockDim.x + threadIdx.x; u < total;
         u += gridDim.x * blockDim.x) {
        const float* src; short* dst; int off;
        if (u < NX4)            { src = x;  dst = xb;  off = u; }
        else if (u < NX4 + NQ4) { src = wq; dst = wqb; off = u - NX4; }
        else                    { src = wo; dst = wob; off = u - NX4 - NQ4; }
        f32x4 v = *(const f32x4*)&src[(size_t)off * 4];
        s16x4 o;
        o[0] = f2b(v[0]); o[1] = f2b(v[1]); o[2] = f2b(v[2]); o[3] = f2b(v[3]);
        *(s16x4*)&dst[(size_t)off * 4] = o;
    }
}

// ---------------------------------------------------------------------------
// GEMM (C = A * B^T), m97 pattern: 128x128 tile, BK=64, 4 waves.
// QKV=true: scatter to Q (scaled, (B,H,T,DK)), K ((B,H,T,DK)), Vt ((B,H,DK,T)).
// QKV=false: write C as FP32 to Cf (d_out is float per reference dtype).
// ---------------------------------------------------------------------------
template<bool QKV>
__global__ __launch_bounds__(256)
void gemm_bt(const short* __restrict__ A, const short* __restrict__ Bm,
             int M, int N, int K,
             short* __restrict__ C0, short* __restrict__ C1, short* __restrict__ C2,
             float* __restrict__ Cf)
{
    __shared__ short As[128 * 64];
    __shared__ short Bs[128 * 64];
    const int tid  = threadIdx.x;
    const int lane = tid & 63;
    const int lr   = lane & 15;
    const int lg   = lane >> 4;
    const int wid  = tid >> 6;
    const int wr   = wid >> 1, wc = wid & 1;
    const long row0 = (long)blockIdx.y * 128;
    const long col0 = (long)blockIdx.x * 128;

    f32x4 acc[4][4] = {};

    for (int k0 = 0; k0 < K; k0 += 64) {
        #pragma unroll
        for (int i = 0; i < 4; ++i) {               // A tile: 128x64 bf16
            int off = (i * 256 + tid) * 8;
            int r = off >> 6, c = off & 63;
            ld16(&A[(row0 + r) * (long)K + k0 + c], &As[off]);
        }
        #pragma unroll
        for (int i = 0; i < 4; ++i) {               // B tile: 128x64 bf16
            int off = (i * 256 + tid) * 8;
            int r = off >> 6, c = off & 63;
            ld16(&Bm[(col0 + r) * (long)K + k0 + c], &Bs[off]);
        }
        __syncthreads();
        #pragma unroll
        for (int ks = 0; ks < 2; ++ks) {
            bf16x8 af[4], bfr[4];
            #pragma unroll
            for (int m = 0; m < 4; ++m)
                af[m] = ldb(&As[(wr*64 + m*16 + lr)*64 + ks*32 + lg*8]);
            #pragma unroll
            for (int n = 0; n < 4; ++n)
                bfr[n] = ldb(&Bs[(wc*64 + n*16 + lr)*64 + ks*32 + lg*8]);
            #pragma unroll
            for (int m = 0; m < 4; ++m)
                #pragma unroll
                for (int n = 0; n < 4; ++n)
                    acc[m][n] = __builtin_amdgcn_mfma_f32_16x16x32_bf16(
                        af[m], bfr[n], acc[m][n], 0, 0, 0);
        }
        __syncthreads();
    }

    // C/D layout: col = lane&15, row = (lane>>4)*4 + reg
    if (QKV) {
        #pragma unroll
        for (int n = 0; n < 4; ++n) {
            const int gn    = (int)col0 + wc*64 + n*16 + lr;   // 0..3071
            const int which = gn >> 10;                        // 0=Q 1=K 2=V
            const int wi    = gn & 1023;
            const int h = wi >> 6, dk = wi & 63;
            #pragma unroll
            for (int m = 0; m < 4; ++m) {
                const int gm0 = (int)row0 + wr*64 + m*16 + lg*4;
                const int b = gm0 >> 11, t0 = gm0 & 2047;
                if (which == 2) {
                    s16x4 v4;
                    #pragma unroll
                    for (int r = 0; r < 4; ++r) v4[r] = f2b(acc[m][n][r]);
                    *(s16x4*)&C2[((long)((b*NH + h)*DK + dk)) * SEQ + t0] = v4;
                } else {
                    short* dst = (which == 0) ? C0 : C1;
                    const float sc = (which == 0) ? QSCALE : 1.0f;
                    #pragma unroll
                    for (int r = 0; r < 4; ++r)
                        dst[((long)((b*NH + h)*SEQ + t0 + r)) * DK + dk] =
                            f2b(acc[m][n][r] * sc);
                }
            }
        }
    } else {
        #pragma unroll
        for (int m = 0; m < 4; ++m)
            #pragma unroll
            for (int r = 0; r < 4; ++r) {
                const long gm = row0 + wr*64 + m*16 + lg*4 + r;
                #pragma unroll
                for (int n = 0; n < 4; ++n)
                    Cf[gm * N + col0 + wc*64 + n*16 + lr] = acc[m][n][r];
            }
    }
}

// ---------------------------------------------------------------------------
// Kernel 3: causal flash attention, swapped-operand, register-pipelined.
// grid = (SEQ/128, BATCH*NH), block = 256 (4 waves, 32 q-rows per wave).
// blockIdx.x reversed (longest blocks first). __launch_bounds__(256,2) so the
// compiler keeps the 16 staging fragments (K next tile + V current) in VGPRs.
//
// S^T = mfma(K,Q): lane owns q = lane&15 for two q-groups (A: qbase+lr,
// B: qbase+16+lr) sharing the same K/V fragments. Online softmax lane-local
// + 2 shfl. O^T = mfma(Vt,P) keeps q = lane&15. P transposed via LDS.
// ---------------------------------------------------------------------------
__global__ __launch_bounds__(256, 2)
void attn(const short* __restrict__ Qb, const short* __restrict__ Kb,
          const short* __restrict__ Vt, short* __restrict__ Ob)
{
    __shared__ short Pl[4][2][16 * 72];   // [wave][qgroup][16 rows x stride 72]
    const int tid  = threadIdx.x;
    const int lane = tid & 63;
    const int lr   = lane & 15, lg = lane >> 4;
    const int wid  = tid >> 6;
    const int bh   = blockIdx.y;
    const int b    = bh >> 4, h = bh & 15;
    const int qbase = (15 - (int)blockIdx.x) * 128 + wid * 32;

    const short* Qh = Qb + (long)bh * (SEQ * DK);
    const short* Kh = Kb + (long)bh * (SEQ * DK);
    const short* Vh = Vt + (long)bh * (DK * SEQ);
    short* PwA = &Pl[wid][0][0];
    short* PwB = &Pl[wid][1][0];

    // Q B-operand fragments for both q-groups
    const bf16x8 qfA0 = ldb(&Qh[(qbase + lr) * DK + lg * 8]);
    const bf16x8 qfA1 = ldb(&Qh[(qbase + lr) * DK + 32 + lg * 8]);
    const bf16x8 qfB0 = ldb(&Qh[(qbase + 16 + lr) * DK + lg * 8]);
    const bf16x8 qfB1 = ldb(&Qh[(qbase + 16 + lr) * DK + 32 + lg * 8]);

    f32x4 oA[4] = {}, oB[4] = {};
    float mA = -1e30f, lA = 0.f, mB = -1e30f, lB = 0.f;

    const int ntiles = ((qbase + 31) >> 6) + 1;   // 64-key tiles incl. diagonal

    // prologue: K(0) into registers (batched: 8 independent dwordx4 loads)
    bf16x8 kreg[8];
    #pragma unroll
    for (int kt = 0; kt < 4; ++kt) {
        kreg[kt*2]   = ldb(&Kh[(kt*16 + lr) * DK + lg * 8]);
        kreg[kt*2+1] = ldb(&Kh[(kt*16 + lr) * DK + 32 + lg * 8]);
    }

    for (int t = 0; t < ntiles; ++t) {
        const int k0 = t << 6;
        // ---- S^T for both q-groups from resident K fragments
        f32x4 sA[4], sB[4];
        __builtin_amdgcn_s_setprio(1);
        #pragma unroll
        for (int kt = 0; kt < 4; ++kt) {
            f32x4 zA = {}, zB = {};
            zA = __builtin_amdgcn_mfma_f32_16x16x32_bf16(kreg[kt*2],   qfA0, zA, 0, 0, 0);
            sA[kt] = __builtin_amdgcn_mfma_f32_16x16x32_bf16(kreg[kt*2+1], qfA1, zA, 0, 0, 0);
            zB = __builtin_amdgcn_mfma_f32_16x16x32_bf16(kreg[kt*2],   qfB0, zB, 0, 0, 0);
            sB[kt] = __builtin_amdgcn_mfma_f32_16x16x32_bf16(kreg[kt*2+1], qfB1, zB, 0, 0, 0);
        }
        __builtin_amdgcn_s_setprio(0);
        // ---- prefetch: V(t) now, K(t+1) into kreg (WAR after S-MFMAs)
        bf16x8 vreg[8];
        #pragma unroll
        for (int n2 = 0; n2 < 4; ++n2) {
            vreg[n2*2]   = ldb(&Vh[(n2*16 + lr) * SEQ + k0 + lg*8]);
            vreg[n2*2+1] = ldb(&Vh[(n2*16 + lr) * SEQ + k0 + 32 + lg*8]);
        }
        if (t + 1 < ntiles) {
            #pragma unroll
            for (int kt = 0; kt < 4; ++kt) {
                kreg[kt*2]   = ldb(&Kh[(k0 + 64 + kt*16 + lr) * DK + lg*8]);
                kreg[kt*2+1] = ldb(&Kh[(k0 + 64 + kt*16 + lr) * DK + 32 + lg*8]);
            }
        }
        // ---- causal mask (diagonal tile only; both groups' diagonals are here)
        if (t == ntiles - 1) {
            #pragma unroll
            for (int kt = 0; kt < 4; ++kt)
                #pragma unroll
                for (int r = 0; r < 4; ++r) {
                    const int kk = k0 + kt*16 + lg*4 + r;
                    if (kk > qbase + lr)      sA[kt][r] = -1e30f;
                    if (kk > qbase + 16 + lr) sB[kt][r] = -1e30f;
                }
        }
        // ---- online softmax, group A (lane-local 16 + 2 shfl)
        {
            float tm = sA[0][0];
            #pragma unroll
            for (int kt = 0; kt < 4; ++kt)
                #pragma unroll
                for (int r = 0; r < 4; ++r) tm = fmaxf(tm, sA[kt][r]);
            tm = fmaxf(tm, __shfl_xor(tm, 16));
            tm = fmaxf(tm, __shfl_xor(tm, 32));
            const float mnew = fmaxf(mA, tm);
            const float corr = exp2f(mA - mnew);
            mA = mnew;
            float rs = 0.f;
            #pragma unroll
            for (int kt = 0; kt < 4; ++kt) {
                s16x4 pk;
                #pragma unroll
                for (int r = 0; r < 4; ++r) {
                    const float p = exp2f(sA[kt][r] - mnew);
                    rs += p; pk[r] = f2b(p);
                }
                *(s16x4*)&PwA[lr*72 + kt*16 + lg*4] = pk;
            }
            rs += __shfl_xor(rs, 16);
            rs += __shfl_xor(rs, 32);
            lA = lA * corr + rs;
            #pragma unroll
            for (int n2 = 0; n2 < 4; ++n2) oA[n2] *= corr;
        }
        // ---- online softmax, group B
        {
            float tm = sB[0][0];
            #pragma unroll
            for (int kt = 0; kt < 4; ++kt)
                #pragma unroll
                for (int r = 0; r < 4; ++r) tm = fmaxf(tm, sB[kt][r]);
            tm = fmaxf(tm, __shfl_xor(tm, 16));
            tm = fmaxf(tm, __shfl_xor(tm, 32));
            const float mnew = fmaxf(mB, tm);
            const float corr = exp2f(mB - mnew);
            mB = mnew;
            float rs = 0.f;
            #pragma unroll
            for (int kt = 0; kt < 4; ++kt) {
                s16x4 pk;
                #pragma unroll
                for (int r = 0; r < 4; ++r) {
                    const float p = exp2f(sB[kt][r] - mnew);
                    rs += p; pk[r] = f2b(p);
                }
                *(s16x4*)&PwB[lr*72 + kt*16 + lg*4] = pk;
            }
            rs += __shfl_xor(rs, 16);
            rs += __shfl_xor(rs, 32);
            lB = lB * corr + rs;
            #pragma unroll
            for (int n2 = 0; n2 < 4; ++n2) oB[n2] *= corr;
        }
        // ---- P transpose handoff (verified fence pattern)
        __builtin_amdgcn_sched_barrier(0);
        __builtin_amdgcn_s_waitcnt(0xC07F);   // lgkmcnt(0)
        __builtin_amdgcn_sched_barrier(0);
        const bf16x8 pfA0 = ldb(&PwA[lr*72 + lg*8]);
        const bf16x8 pfA1 = ldb(&PwA[lr*72 + 32 + lg*8]);
        const bf16x8 pfB0 = ldb(&PwB[lr*72 + lg*8]);
        const bf16x8 pfB1 = ldb(&PwB[lr*72 + 32 + lg*8]);
        // ---- O^T += Vt * P^T for both groups (V frags shared)
        __builtin_amdgcn_s_setprio(1);
        #pragma unroll
        for (int n2 = 0; n2 < 4; ++n2) {
            oA[n2] = __builtin_amdgcn_mfma_f32_16x16x32_bf16(vreg[n2*2],   pfA0, oA[n2], 0, 0, 0);
            oA[n2] = __builtin_amdgcn_mfma_f32_16x16x32_bf16(vreg[n2*2+1], pfA1, oA[n2], 0, 0, 0);
            oB[n2] = __builtin_amdgcn_mfma_f32_16x16x32_bf16(vreg[n2*2],   pfB0, oB[n2], 0, 0, 0);
            oB[n2] = __builtin_amdgcn_mfma_f32_16x16x32_bf16(vreg[n2*2+1], pfB1, oB[n2], 0, 0, 0);
        }
        __builtin_amdgcn_s_setprio(0);
    }

    const float invA = 1.0f / lA;
    const float invB = 1.0f / lB;
    const long orowA = ((long)(b * SEQ + qbase + lr)) * DIM + h * DK;
    const long orowB = ((long)(b * SEQ + qbase + 16 + lr)) * DIM + h * DK;
    #pragma unroll
    for (int n2 = 0; n2 < 4; ++n2) {
        s16x4 ovA, ovB;
        #pragma unroll
        for (int r = 0; r < 4; ++r) {
            ovA[r] = f2b(oA[n2][r] * invA);
            ovB[r] = f2b(oB[n2][r] * invB);
        }
        *(s16x4*)&Ob[orowA + n2*16 + lg*4] = ovA;
        *(s16x4*)&Ob[orowB + n2*16 + lg*4] = ovB;
    }
}

// ---------------------------------------------------------------------------
extern "C" void kernel_launch(void* const* d_in, const int* in_sizes, int n_in,
                              void* d_out, int out_size, void* d_ws, size_t ws_size,
                              hipStream_t stream) {
    // Inputs are FP32 (reference dtypes). Select by size to be order-robust.
    const float *x = nullptr, *wqkv = nullptr, *wo = nullptr;
    for (int i = 0; i < n_in; ++i) {
        if      (in_sizes[i] == BATCH*SEQ*DIM) x    = (const float*)d_in[i];
        else if (in_sizes[i] == 3*DIM*DIM)     wqkv = (const float*)d_in[i];
        else if (in_sizes[i] == DIM*DIM)       wo   = (const float*)d_in[i];
    }
    float* out = (float*)d_out;   // FP32 output (reference output dtype)

    // Workspace (72 MiB; Ob aliases Xb which is dead after the QKV GEMM)
    char* ws = (char*)d_ws;
    short* Xb  = (short*)(ws);                        // [ 0,16) MiB x bf16
    short* Wqb = (short*)(ws + (16u<<20));            // [16,22) W_qkv bf16
    short* Wob = (short*)(ws + (22u<<20));            // [22,24) W_o bf16
    short* Qb  = (short*)(ws + (24u<<20));            // [24,40) Q (B,H,T,DK) scaled
    short* Kb  = (short*)(ws + (40u<<20));            // [40,56) K (B,H,T,DK)
    short* Vt  = (short*)(ws + (56u<<20));            // [56,72) V (B,H,DK,T)
    short* Ob  = Xb;                                  // attn out (B,T,D)

    cvt_all<<<2048, 256, 0, stream>>>(x, wqkv, wo, Xb, Wqb, Wob);

    // QKV projection: M=8192, N=3072, K=1024
    gemm_bt<true><<<dim3(3*DIM/128, BATCH*SEQ/128), 256, 0, stream>>>(
        Xb, Wqb, BATCH*SEQ, 3*DIM, DIM, Qb, Kb, Vt, nullptr);

    attn<<<dim3(SEQ/128, BATCH*NH), 256, 0, stream>>>(Qb, Kb, Vt, Ob);

    // Output projection: M=8192, N=1024, K=1024 -> FP32 d_out
    gemm_bt<false><<<dim3(DIM/128, BATCH*SEQ/128), 256, 0, stream>>>(
        Ob, Wob, BATCH*SEQ, DIM, DIM, nullptr, nullptr, nullptr, out);
}

// Round 9
// 353.615 us; speedup vs baseline: 1.8420x; 1.2069x over previous
//
#include <hip/hip_runtime.h>

// Problem constants (B,T,D,H fixed by the reference)
#define BATCH 4
#define SEQ   2048
#define DIM   1024
#define NH    16
#define DK    64
// 0.125 (1/sqrt(DK)) * log2(e): folded into Q so attention uses exp2f
#define QSCALE 0.18033688011112042f

typedef __bf16 bf16x8 __attribute__((ext_vector_type(8)));
typedef float  f32x4  __attribute__((ext_vector_type(4)));
typedef short  s16x4  __attribute__((ext_vector_type(4)));
typedef short  s16x8  __attribute__((ext_vector_type(8)));

__device__ __forceinline__ short f2b(float f) {
    unsigned u = __float_as_uint(f);
    u += 0x7FFFu + ((u >> 16) & 1u);   // RNE
    return (short)(u >> 16);
}

// Load 8 bf16 as shorts, bit-cast in-register (no type-punned memory access).
__device__ __forceinline__ bf16x8 ldb(const short* p) {
    s16x8 v = *(const s16x8*)p;
    return __builtin_bit_cast(bf16x8, v);
}

// async global->LDS, 16B per lane. LDS dest must be linear in lane order.
__device__ __forceinline__ void ld16(const void* g, void* l) {
    __builtin_amdgcn_global_load_lds(
        (__attribute__((address_space(1))) void*)(unsigned long long)g,
        (__attribute__((address_space(3))) void*)l, 16, 0, 0);
}

// ---------------------------------------------------------------------------
// Kernel 1: fp32 -> bf16 conversion of x, W_qkv, W_o
// ---------------------------------------------------------------------------
__global__ __launch_bounds__(256)
void cvt_all(const float* __restrict__ x, const float* __restrict__ wq,
             const float* __restrict__ wo,
             short* __restrict__ xb, short* __restrict__ wqb, short* __restrict__ wob)
{
    const int NX4 = (BATCH*SEQ*DIM) / 4;
    const int NQ4 = (3*DIM*DIM) / 4;
    const int NO4 = (DIM*DIM) / 4;
    const int total = NX4 + NQ4 + NO4;
    for (int u = blockIdx.x * blockDim.x + threadIdx.x; u < total;
         u += gridDim.x * blockDim.x) {
        const float* src; short* dst; int off;
        if (u < NX4)            { src = x;  dst = xb;  off = u; }
        else if (u < NX4 + NQ4) { src = wq; dst = wqb; off = u - NX4; }
        else                    { src = wo; dst = wob; off = u - NX4 - NQ4; }
        f32x4 v = *(const f32x4*)&src[(size_t)off * 4];
        s16x4 o;
        o[0] = f2b(v[0]); o[1] = f2b(v[1]); o[2] = f2b(v[2]); o[3] = f2b(v[3]);
        *(s16x4*)&dst[(size_t)off * 4] = o;
    }
}

// ---------------------------------------------------------------------------
// GEMM (C = A * B^T), m97 pattern: 128x128 tile, BK=64, 4 waves.
// QKV=true: scatter to Q (scaled, (B,H,T,DK)), K ((B,H,T,DK)), Vt ((B,H,DK,T)).
// QKV=false: write C as FP32 to Cf (d_out is float per reference dtype).
// ---------------------------------------------------------------------------
template<bool QKV>
__global__ __launch_bounds__(256)
void gemm_bt(const short* __restrict__ A, const short* __restrict__ Bm,
             int M, int N, int K,
             short* __restrict__ C0, short* __restrict__ C1, short* __restrict__ C2,
             float* __restrict__ Cf)
{
    __shared__ short As[128 * 64];
    __shared__ short Bs[128 * 64];
    const int tid  = threadIdx.x;
    const int lane = tid & 63;
    const int lr   = lane & 15;
    const int lg   = lane >> 4;
    const int wid  = tid >> 6;
    const int wr   = wid >> 1, wc = wid & 1;
    const long row0 = (long)blockIdx.y * 128;
    const long col0 = (long)blockIdx.x * 128;

    f32x4 acc[4][4] = {};

    for (int k0 = 0; k0 < K; k0 += 64) {
        #pragma unroll
        for (int i = 0; i < 4; ++i) {               // A tile: 128x64 bf16
            int off = (i * 256 + tid) * 8;
            int r = off >> 6, c = off & 63;
            ld16(&A[(row0 + r) * (long)K + k0 + c], &As[off]);
        }
        #pragma unroll
        for (int i = 0; i < 4; ++i) {               // B tile: 128x64 bf16
            int off = (i * 256 + tid) * 8;
            int r = off >> 6, c = off & 63;
            ld16(&Bm[(col0 + r) * (long)K + k0 + c], &Bs[off]);
        }
        __syncthreads();
        #pragma unroll
        for (int ks = 0; ks < 2; ++ks) {
            bf16x8 af[4], bfr[4];
            #pragma unroll
            for (int m = 0; m < 4; ++m)
                af[m] = ldb(&As[(wr*64 + m*16 + lr)*64 + ks*32 + lg*8]);
            #pragma unroll
            for (int n = 0; n < 4; ++n)
                bfr[n] = ldb(&Bs[(wc*64 + n*16 + lr)*64 + ks*32 + lg*8]);
            #pragma unroll
            for (int m = 0; m < 4; ++m)
                #pragma unroll
                for (int n = 0; n < 4; ++n)
                    acc[m][n] = __builtin_amdgcn_mfma_f32_16x16x32_bf16(
                        af[m], bfr[n], acc[m][n], 0, 0, 0);
        }
        __syncthreads();
    }

    // C/D layout: col = lane&15, row = (lane>>4)*4 + reg
    if (QKV) {
        #pragma unroll
        for (int n = 0; n < 4; ++n) {
            const int gn    = (int)col0 + wc*64 + n*16 + lr;   // 0..3071
            const int which = gn >> 10;                        // 0=Q 1=K 2=V
            const int wi    = gn & 1023;
            const int h = wi >> 6, dk = wi & 63;
            #pragma unroll
            for (int m = 0; m < 4; ++m) {
                const int gm0 = (int)row0 + wr*64 + m*16 + lg*4;
                const int b = gm0 >> 11, t0 = gm0 & 2047;
                if (which == 2) {
                    s16x4 v4;
                    #pragma unroll
                    for (int r = 0; r < 4; ++r) v4[r] = f2b(acc[m][n][r]);
                    *(s16x4*)&C2[((long)((b*NH + h)*DK + dk)) * SEQ + t0] = v4;
                } else {
                    short* dst = (which == 0) ? C0 : C1;
                    const float sc = (which == 0) ? QSCALE : 1.0f;
                    #pragma unroll
                    for (int r = 0; r < 4; ++r)
                        dst[((long)((b*NH + h)*SEQ + t0 + r)) * DK + dk] =
                            f2b(acc[m][n][r] * sc);
                }
            }
        }
    } else {
        #pragma unroll
        for (int m = 0; m < 4; ++m)
            #pragma unroll
            for (int r = 0; r < 4; ++r) {
                const long gm = row0 + wr*64 + m*16 + lg*4 + r;
                #pragma unroll
                for (int n = 0; n < 4; ++n)
                    Cf[gm * N + col0 + wc*64 + n*16 + lr] = acc[m][n][r];
            }
    }
}

// ---------------------------------------------------------------------------
// Kernel 3: causal flash attention, swapped-operand, LDS-staged K/V.
// grid = (SEQ/128, BATCH*NH), block = 256 (4 waves, 32 q-rows per wave).
// blockIdx.x reversed (longest blocks first).
//
// Per 64-key tile: K/V staged into LDS once per BLOCK (global_load_lds,
// double-buffered, counted vmcnt(4), raw s_barrier — 2-phase pipeline).
// LDS layout XOR-swizzled (col16 ^= row&7): linear dest + pre-swizzled
// global source + swizzled ds_read (rule #21).
// S^T = mfma(K,Q): lane owns q = lane&15 (2 q-groups). Softmax lane-local
// + 2 shfl. O^T = mfma(Vt,P). P transposed via per-wave LDS.
// ---------------------------------------------------------------------------
__global__ __launch_bounds__(256, 3)
void attn(const short* __restrict__ Qb, const short* __restrict__ Kb,
          const short* __restrict__ Vt, short* __restrict__ Ob)
{
    __shared__ short Ks[2][64 * 64];      // 2 x 8 KB, swizzled
    __shared__ short Vs[2][64 * 64];      // 2 x 8 KB, swizzled
    __shared__ short Pl[4][2][16 * 72];   // per-wave P buffers
    const int tid  = threadIdx.x;
    const int lane = tid & 63;
    const int lr   = lane & 15, lg = lane >> 4;
    const int wid  = tid >> 6;
    const int bh   = blockIdx.y;
    const int b    = bh >> 4, h = bh & 15;
    const int qb0  = (15 - (int)blockIdx.x) * 128;
    const int qbase = qb0 + wid * 32;
    const int NT   = (qb0 >> 6) + 2;      // 64-key tiles covering 0..qb0+127

    const short* Qh = Qb + (long)bh * (SEQ * DK);
    const short* Kh = Kb + (long)bh * (SEQ * DK);
    const short* Vh = Vt + (long)bh * (DK * SEQ);
    short* PwA = &Pl[wid][0][0];
    short* PwB = &Pl[wid][1][0];

    // Q B-operand fragments for both q-groups (drained by prologue vmcnt(0))
    const bf16x8 qfA0 = ldb(&Qh[(qbase + lr) * DK + lg * 8]);
    const bf16x8 qfA1 = ldb(&Qh[(qbase + lr) * DK + 32 + lg * 8]);
    const bf16x8 qfB0 = ldb(&Qh[(qbase + 16 + lr) * DK + lg * 8]);
    const bf16x8 qfB1 = ldb(&Qh[(qbase + 16 + lr) * DK + 32 + lg * 8]);

    f32x4 oA[4] = {}, oB[4] = {};
    float mA = -1e30f, lA = 0.f, mB = -1e30f, lB = 0.f;

    // stage tile k0 into buffer bufi: 4 ld16 per thread (K x2, V x2).
    // source pre-swizzled so swizzled LDS layout lands from linear dest.
    #define STAGE(bufi, k0_)                                                  \
        {                                                                     \
            _Pragma("unroll")                                                 \
            for (int i_ = 0; i_ < 2; ++i_) {                                  \
                const int idx_ = i_ * 256 + tid;     /* 16B unit, 0..511 */   \
                const int row_ = idx_ >> 3;                                   \
                const int sc_  = ((idx_ & 7) ^ (row_ & 7)) * 8;               \
                ld16(&Kh[(k0_ + row_) * DK + sc_], &Ks[bufi][idx_ * 8]);      \
                ld16(&Vh[row_ * SEQ + (k0_) + sc_], &Vs[bufi][idx_ * 8]);     \
            }                                                                 \
        }

    // prologue: stage tile 0, drain everything (incl. Q loads), align
    STAGE(0, 0)
    __builtin_amdgcn_s_waitcnt(0x0F70);   // vmcnt(0)
    __builtin_amdgcn_sched_barrier(0);
    __builtin_amdgcn_s_barrier();

    int cur = 0;
    for (int t = 0; t < NT; ++t) {
        const int k0 = t << 6;
        // issue next tile's stage (stays in flight across compute)
        if (t + 1 < NT) {
            STAGE(cur ^ 1, k0 + 64)
            __builtin_amdgcn_s_waitcnt(0x0F74);   // vmcnt(4): cur's loads done
        } else {
            __builtin_amdgcn_s_waitcnt(0x0F70);   // vmcnt(0)
        }
        __builtin_amdgcn_sched_barrier(0);
        __builtin_amdgcn_s_barrier();             // cur buffer ready for all
        __builtin_amdgcn_sched_barrier(0);

        if (k0 <= qbase + 31) {                   // wave-uniform compute gate
            const int rswz = lr & 7;
            // ---- K fragments from swizzled LDS
            bf16x8 kf[4][2];
            #pragma unroll
            for (int kt = 0; kt < 4; ++kt) {
                const int row = kt * 16 + lr;
                kf[kt][0] = ldb(&Ks[cur][row * 64 + ((lg)     ^ rswz) * 8]);
                kf[kt][1] = ldb(&Ks[cur][row * 64 + ((4 + lg) ^ rswz) * 8]);
            }
            // ---- S^T for both q-groups
            f32x4 sA[4], sB[4];
            __builtin_amdgcn_s_setprio(1);
            #pragma unroll
            for (int kt = 0; kt < 4; ++kt) {
                f32x4 zA = {}, zB = {};
                zA = __builtin_amdgcn_mfma_f32_16x16x32_bf16(kf[kt][0], qfA0, zA, 0, 0, 0);
                sA[kt] = __builtin_amdgcn_mfma_f32_16x16x32_bf16(kf[kt][1], qfA1, zA, 0, 0, 0);
                zB = __builtin_amdgcn_mfma_f32_16x16x32_bf16(kf[kt][0], qfB0, zB, 0, 0, 0);
                sB[kt] = __builtin_amdgcn_mfma_f32_16x16x32_bf16(kf[kt][1], qfB1, zB, 0, 0, 0);
            }
            __builtin_amdgcn_s_setprio(0);
            // ---- V fragments (issue early; latency hides under softmax)
            bf16x8 vf[4][2];
            #pragma unroll
            for (int n2 = 0; n2 < 4; ++n2) {
                const int row = n2 * 16 + lr;
                vf[n2][0] = ldb(&Vs[cur][row * 64 + ((lg)     ^ rswz) * 8]);
                vf[n2][1] = ldb(&Vs[cur][row * 64 + ((4 + lg) ^ rswz) * 8]);
            }
            // ---- causal mask (only near-diagonal tiles)
            if (k0 + 63 > qbase) {
                #pragma unroll
                for (int kt = 0; kt < 4; ++kt)
                    #pragma unroll
                    for (int r = 0; r < 4; ++r) {
                        const int kk = k0 + kt * 16 + lg * 4 + r;
                        if (kk > qbase + lr)      sA[kt][r] = -1e30f;
                        if (kk > qbase + 16 + lr) sB[kt][r] = -1e30f;
                    }
            }
            // ---- online softmax, group A
            {
                float tm = sA[0][0];
                #pragma unroll
                for (int kt = 0; kt < 4; ++kt)
                    #pragma unroll
                    for (int r = 0; r < 4; ++r) tm = fmaxf(tm, sA[kt][r]);
                tm = fmaxf(tm, __shfl_xor(tm, 16));
                tm = fmaxf(tm, __shfl_xor(tm, 32));
                const float mnew = fmaxf(mA, tm);
                const float corr = exp2f(mA - mnew);
                mA = mnew;
                float rs = 0.f;
                #pragma unroll
                for (int kt = 0; kt < 4; ++kt) {
                    s16x4 pk;
                    #pragma unroll
                    for (int r = 0; r < 4; ++r) {
                        const float p = exp2f(sA[kt][r] - mnew);
                        rs += p; pk[r] = f2b(p);
                    }
                    *(s16x4*)&PwA[lr*72 + kt*16 + lg*4] = pk;
                }
                rs += __shfl_xor(rs, 16);
                rs += __shfl_xor(rs, 32);
                lA = lA * corr + rs;
                #pragma unroll
                for (int n2 = 0; n2 < 4; ++n2) oA[n2] *= corr;
            }
            // ---- online softmax, group B
            {
                float tm = sB[0][0];
                #pragma unroll
                for (int kt = 0; kt < 4; ++kt)
                    #pragma unroll
                    for (int r = 0; r < 4; ++r) tm = fmaxf(tm, sB[kt][r]);
                tm = fmaxf(tm, __shfl_xor(tm, 16));
                tm = fmaxf(tm, __shfl_xor(tm, 32));
                const float mnew = fmaxf(mB, tm);
                const float corr = exp2f(mB - mnew);
                mB = mnew;
                float rs = 0.f;
                #pragma unroll
                for (int kt = 0; kt < 4; ++kt) {
                    s16x4 pk;
                    #pragma unroll
                    for (int r = 0; r < 4; ++r) {
                        const float p = exp2f(sB[kt][r] - mnew);
                        rs += p; pk[r] = f2b(p);
                    }
                    *(s16x4*)&PwB[lr*72 + kt*16 + lg*4] = pk;
                }
                rs += __shfl_xor(rs, 16);
                rs += __shfl_xor(rs, 32);
                lB = lB * corr + rs;
                #pragma unroll
                for (int n2 = 0; n2 < 4; ++n2) oB[n2] *= corr;
            }
            // ---- P transpose handoff (lgkmcnt(0) only — keeps vmem in flight)
            __builtin_amdgcn_sched_barrier(0);
            __builtin_amdgcn_s_waitcnt(0xC07F);
            __builtin_amdgcn_sched_barrier(0);
            const bf16x8 pfA0 = ldb(&PwA[lr*72 + lg*8]);
            const bf16x8 pfA1 = ldb(&PwA[lr*72 + 32 + lg*8]);
            const bf16x8 pfB0 = ldb(&PwB[lr*72 + lg*8]);
            const bf16x8 pfB1 = ldb(&PwB[lr*72 + 32 + lg*8]);
            // ---- O^T += Vt * P^T for both groups
            __builtin_amdgcn_s_setprio(1);
            #pragma unroll
            for (int n2 = 0; n2 < 4; ++n2) {
                oA[n2] = __builtin_amdgcn_mfma_f32_16x16x32_bf16(vf[n2][0], pfA0, oA[n2], 0, 0, 0);
                oA[n2] = __builtin_amdgcn_mfma_f32_16x16x32_bf16(vf[n2][1], pfA1, oA[n2], 0, 0, 0);
                oB[n2] = __builtin_amdgcn_mfma_f32_16x16x32_bf16(vf[n2][0], pfB0, oB[n2], 0, 0, 0);
                oB[n2] = __builtin_amdgcn_mfma_f32_16x16x32_bf16(vf[n2][1], pfB1, oB[n2], 0, 0, 0);
            }
            __builtin_amdgcn_s_setprio(0);
        }

        __builtin_amdgcn_s_barrier();   // all waves done with cur before reuse
        cur ^= 1;
    }

    const float invA = 1.0f / lA;
    const float invB = 1.0f / lB;
    const long orowA = ((long)(b * SEQ + qbase + lr)) * DIM + h * DK;
    const long orowB = ((long)(b * SEQ + qbase + 16 + lr)) * DIM + h * DK;
    #pragma unroll
    for (int n2 = 0; n2 < 4; ++n2) {
        s16x4 ovA, ovB;
        #pragma unroll
        for (int r = 0; r < 4; ++r) {
            ovA[r] = f2b(oA[n2][r] * invA);
            ovB[r] = f2b(oB[n2][r] * invB);
        }
        *(s16x4*)&Ob[orowA + n2*16 + lg*4] = ovA;
        *(s16x4*)&Ob[orowB + n2*16 + lg*4] = ovB;
    }
}

// ---------------------------------------------------------------------------
extern "C" void kernel_launch(void* const* d_in, const int* in_sizes, int n_in,
                              void* d_out, int out_size, void* d_ws, size_t ws_size,
                              hipStream_t stream) {
    // Inputs are FP32 (reference dtypes). Select by size to be order-robust.
    const float *x = nullptr, *wqkv = nullptr, *wo = nullptr;
    for (int i = 0; i < n_in; ++i) {
        if      (in_sizes[i] == BATCH*SEQ*DIM) x    = (const float*)d_in[i];
        else if (in_sizes[i] == 3*DIM*DIM)     wqkv = (const float*)d_in[i];
        else if (in_sizes[i] == DIM*DIM)       wo   = (const float*)d_in[i];
    }
    float* out = (float*)d_out;   // FP32 output (reference output dtype)

    // Workspace (72 MiB; Ob aliases Xb which is dead after the QKV GEMM)
    char* ws = (char*)d_ws;
    short* Xb  = (short*)(ws);                        // [ 0,16) MiB x bf16
    short* Wqb = (short*)(ws + (16u<<20));            // [16,22) W_qkv bf16
    short* Wob = (short*)(ws + (22u<<20));            // [22,24) W_o bf16
    short* Qb  = (short*)(ws + (24u<<20));            // [24,40) Q (B,H,T,DK) scaled
    short* Kb  = (short*)(ws + (40u<<20));            // [40,56) K (B,H,T,DK)
    short* Vt  = (short*)(ws + (56u<<20));            // [56,72) V (B,H,DK,T)
    short* Ob  = Xb;                                  // attn out (B,T,D)

    cvt_all<<<2048, 256, 0, stream>>>(x, wqkv, wo, Xb, Wqb, Wob);

    // QKV projection: M=8192, N=3072, K=1024
    gemm_bt<true><<<dim3(3*DIM/128, BATCH*SEQ/128), 256, 0, stream>>>(
        Xb, Wqb, BATCH*SEQ, 3*DIM, DIM, Qb, Kb, Vt, nullptr);

    attn<<<dim3(SEQ/128, BATCH*NH), 256, 0, stream>>>(Qb, Kb, Vt, Ob);

    // Output projection: M=8192, N=1024, K=1024 -> FP32 d_out
    gemm_bt<false><<<dim3(DIM/128, BATCH*SEQ/128), 256, 0, stream>>>(
        Ob, Wob, BATCH*SEQ, DIM, DIM, nullptr, nullptr, nullptr, out);
}